// Round 4
// baseline (384.580 us; speedup 1.0000x reference)
//
#include <hip/hip_runtime.h>

// Deformable conv2d (N=4, C=OC=256, 80x80, 3x3, s1 p1 d1):
// fused bilinear-im2col + bf16 MFMA GEMM, fp32 accumulate.
// R4: (a) tap-major K ordering (k' = tap*256 + c) -> one tap per 64-chunk,
//     hoists bilinear coeff lookup + kills per-sample division;
//     (b) split-K x2 across grid.z (1600 blocks, 6.25/CU) with fp32
//     atomicAdd epilogue into memset-zeroed out (2 commutative addends ->
//     deterministic); paired-corner dwordx2 gathers; double-buffered LDS.

typedef short short8 __attribute__((ext_vector_type(8)));
typedef float floatx4 __attribute__((ext_vector_type(4)));
typedef float floatx2 __attribute__((ext_vector_type(2)));

#define Cc    256
#define OCc   256
#define Hh    80
#define Ww    80
#define HW    6400
#define KK    9
#define Ktot  2304
#define PT    32            // pixels per block
#define KC    64            // K per chunk (= one tap, 64 channels)
#define NCHUNK (Ktot / KC)  // 36
#define CHPB  (NCHUNK / 2)  // 18 chunks per split-K block
#define NKB   (Ktot / 32)   // 72

__device__ __forceinline__ unsigned short f2bf(float f) {
  unsigned u = __float_as_uint(f);
  u += 0x7FFF + ((u >> 16) & 1);
  return (unsigned short)(u >> 16);
}

// ---- Kernel 1: weight fp32 -> bf16 A-fragments, tap-major K (k'=tap*256+c) --
__global__ void pack_weight(const float* __restrict__ w,
                            unsigned short* __restrict__ wp) {
  const int t = blockIdx.x * 256 + threadIdx.x;   // 73728 threads
  const int lane = t & 63;
  const int ocf  = (t >> 6) & 15;
  const int kb   = t >> 10;
  const int oc   = ocf * 16 + (lane & 15);
  const int k0   = kb * 32 + (lane >> 4) * 8;     // k' base; 8 consecutive k'
  const int tap  = k0 >> 8;                       // constant across the 8
  const int c0   = k0 & 255;
  const float* src = w + (size_t)oc * Ktot + (size_t)c0 * KK + tap;
  short8 pk;
  #pragma unroll
  for (int e = 0; e < 8; ++e) pk[e] = (short)f2bf(src[e * KK]);
  *(short8*)(wp + (size_t)t * 8) = pk;
}

// ---- Kernel 2: fused sampling + MFMA, split-K ----
__global__ __launch_bounds__(256, 6) void dcn_mfma(
    const float* __restrict__ x, const float* __restrict__ offset,
    const unsigned short* __restrict__ wp, float* __restrict__ out) {
  __shared__ unsigned short s_col[2][PT * KC];  // 2 x 4KB, XOR-swizzled [px][k]
  __shared__ float4 s_w[KK * PT];               // corner weights (pre-swapped)
  __shared__ int2   s_i[KK * PT];               // paired-corner row bases

  const int tid  = threadIdx.x;
  const int lane = tid & 63;
  const int wv   = tid >> 6;
  const int n    = blockIdx.y;
  const int p0   = blockIdx.x * PT;
  const int ch0  = blockIdx.z * CHPB;           // split-K: chunks [ch0, ch0+18)

  // ---- Phase 0: bilinear coords; edge handling folded into weights ----
  for (int s = tid; s < KK * PT; s += 256) {
    const int k = s / PT, p = s % PT;
    const int pp = p0 + p;
    const int oy = pp / Ww, ox = pp % Ww;
    const int ky = k / 3, kx = k % 3;
    const float offy = offset[(size_t)(n * 18 + 2 * k    ) * HW + pp];
    const float offx = offset[(size_t)(n * 18 + 2 * k + 1) * HW + pp];
    const float py = offy + (float)(ky + oy - 1);
    const float px = offx + (float)(kx + ox - 1);
    const float fy0 = floorf(py), fx0 = floorf(px);
    const int iy0 = (int)fy0, ix0 = (int)fx0;
    const float wy1 = py - fy0, wx1 = px - fx0;
    const float wy0 = 1.f - wy1, wx0 = 1.f - wx1;
    const bool my0 = (iy0     >= 0) & (iy0     < Hh);
    const bool my1 = (iy0 + 1 >= 0) & (iy0 + 1 < Hh);
    const bool mx0 = (ix0     >= 0) & (ix0     < Ww);
    const bool mx1 = (ix0 + 1 >= 0) & (ix0 + 1 < Ww);
    const int cy0 = min(max(iy0,     0), Hh - 1);
    const int cy1 = min(max(iy0 + 1, 0), Hh - 1);
    const int bx  = min(max(ix0, 0), Ww - 2);   // dwordx2 base: [bx, bx+1]
    const bool sel = (ix0 == bx);
    const float wa = wx0 * wy0 * ((my0 && mx0) ? 1.f : 0.f);
    const float wb = wx1 * wy0 * ((my0 && mx1) ? 1.f : 0.f);
    const float wc = wx0 * wy1 * ((my1 && mx0) ? 1.f : 0.f);
    const float wd = wx1 * wy1 * ((my1 && mx1) ? 1.f : 0.f);
    float4 w4;
    w4.x = sel ? wa : wb;  w4.y = sel ? wb : wa;
    w4.z = sel ? wc : wd;  w4.w = sel ? wd : wc;
    s_w[s] = w4;
    s_i[s] = make_int2(cy0 * Ww + bx, cy1 * Ww + bx);
  }

  floatx4 acc[4][2] = {};
  const int lm = lane & 15, lg = lane >> 4;
  const int spx  = tid & 31;        // sampling pixel
  const int skc0 = (tid >> 5) * 8;  // 8 consecutive k' per thread (one tap)
  __syncthreads();

  // ---- Prologue: sample chunk ch0 into buffer 0 ----
  {
    const int tap = ch0 >> 2, cb = (ch0 & 3) * KC;
    const float4 w4 = s_w[tap * PT + spx];
    const int2   o2 = s_i[tap * PT + spx];
    const float* xp = x + (size_t)(n * Cc + cb + skc0) * HW;
    floatx2 ga[8], gb[8];
    #pragma unroll
    for (int i = 0; i < 8; ++i) {
      ga[i] = *(const floatx2*)(xp + (size_t)i * HW + o2.x);
      gb[i] = *(const floatx2*)(xp + (size_t)i * HW + o2.y);
    }
    short8 pk;
    #pragma unroll
    for (int i = 0; i < 8; ++i) {
      const float v = w4.x * ga[i].x + w4.y * ga[i].y
                    + w4.z * gb[i].x + w4.w * gb[i].y;
      pk[i] = (short)f2bf(v);
    }
    const int byte = spx * 128 + ((skc0 * 2) ^ ((spx & 7) << 4));
    *(short8*)((char*)s_col[0] + byte) = pk;
  }
  __syncthreads();

  // ---- Main pipeline over this block's 18 chunks ----
  for (int cl = 0; cl < CHPB; ++cl) {
    const int ch = ch0 + cl;
    const int cur = cl & 1;
    const bool more = (cl + 1 < CHPB);

    // 1) issue next chunk's gathers -> registers
    floatx2 ga[8], gb[8];
    float4 w4n;
    if (more) {
      const int chn = ch + 1;
      const int tap = chn >> 2, cb = (chn & 3) * KC;
      w4n = s_w[tap * PT + spx];
      const int2 o2 = s_i[tap * PT + spx];
      const float* xp = x + (size_t)(n * Cc + cb + skc0) * HW;
      #pragma unroll
      for (int i = 0; i < 8; ++i) {
        ga[i] = *(const floatx2*)(xp + (size_t)i * HW + o2.x);
        gb[i] = *(const floatx2*)(xp + (size_t)i * HW + o2.y);
      }
    }

    // 2) MFMA on current buffer
    const int kb0 = ch * 2;
    #pragma unroll
    for (int ks = 0; ks < 2; ++ks) {
      short8 b[2];
      #pragma unroll
      for (int j = 0; j < 2; ++j) {
        const int px = j * 16 + lm;
        const int byte = px * 128 + (((ks * 64) + lg * 16) ^ ((px & 7) << 4));
        b[j] = *(const short8*)((const char*)s_col[cur] + byte);
      }
      const size_t abase = (size_t)(kb0 + ks) * 16 * 64 * 8;
      #pragma unroll
      for (int f = 0; f < 4; ++f) {
        const int ocf = wv * 4 + f;
        const short8 a = *(const short8*)(wp + abase + (size_t)(ocf * 64 + lane) * 8);
        acc[f][0] = __builtin_amdgcn_mfma_f32_16x16x32_bf16(a, b[0], acc[f][0], 0, 0, 0);
        acc[f][1] = __builtin_amdgcn_mfma_f32_16x16x32_bf16(a, b[1], acc[f][1], 0, 0, 0);
      }
    }

    // 3) bilinear + pack + single b128 write into the other buffer
    if (more) {
      short8 pk;
      #pragma unroll
      for (int i = 0; i < 8; ++i) {
        const float v = w4n.x * ga[i].x + w4n.y * ga[i].y
                      + w4n.z * gb[i].x + w4n.w * gb[i].y;
        pk[i] = (short)f2bf(v);
      }
      const int byte = spx * 128 + ((skc0 * 2) ^ ((spx & 7) << 4));
      *(short8*)((char*)s_col[cur ^ 1] + byte) = pk;
    }
    __syncthreads();
  }

  // ---- Epilogue: atomicAdd partials (2 split-K contributions, commutative) --
  #pragma unroll
  for (int f = 0; f < 4; ++f) {
    const int oc = wv * 64 + f * 16 + lg * 4;
    #pragma unroll
    for (int j = 0; j < 2; ++j) {
      const int px = p0 + j * 16 + lm;
      #pragma unroll
      for (int r = 0; r < 4; ++r) {
        atomicAdd(&out[(size_t)(n * OCc + oc + r) * HW + px], acc[f][j][r]);
      }
    }
  }
}

extern "C" void kernel_launch(void* const* d_in, const int* in_sizes, int n_in,
                              void* d_out, int out_size, void* d_ws, size_t ws_size,
                              hipStream_t stream) {
  const float* x      = (const float*)d_in[0];
  const float* offset = (const float*)d_in[1];
  const float* weight = (const float*)d_in[2];
  float* out = (float*)d_out;
  unsigned short* wp = (unsigned short*)d_ws;

  hipMemsetAsync(out, 0, (size_t)out_size * sizeof(float), stream);
  pack_weight<<<dim3(NKB * 16 * 64 / 256), dim3(256), 0, stream>>>(weight, wp);
  dcn_mfma<<<dim3(HW / PT, 4, 2), dim3(256), 0, stream>>>(x, offset, wp, out);
}

// Round 5
// 226.526 us; speedup vs baseline: 1.6977x; 1.6977x over previous
//
#include <hip/hip_runtime.h>

// Deformable conv2d (N=4, C=OC=256, 80x80, 3x3, s1 p1 d1):
// fused bilinear-im2col + bf16 MFMA GEMM, fp32 accumulate.
// R5: R3 structure (channel-inner k=c*9+tap for tap-locality: FETCH ~107MB),
//     + split-K x2 over CHANNELS (no duplicated x traffic) -> 1600 blocks,
//     atomicAdd epilogue into memset-zeroed out (2 addends, deterministic).

typedef short short8 __attribute__((ext_vector_type(8)));
typedef float floatx4 __attribute__((ext_vector_type(4)));
typedef float floatx2 __attribute__((ext_vector_type(2)));

#define Cc    256
#define OCc   256
#define Hh    80
#define Ww    80
#define HW    6400
#define KK    9
#define Ktot  2304
#define PT    32            // pixels per block
#define KC    64            // K per chunk
#define NCHUNK (Ktot / KC)  // 36
#define CHPB  (NCHUNK / 2)  // 18 chunks per split-K block
#define NKB   (Ktot / 32)   // 72

__device__ __forceinline__ unsigned short f2bf(float f) {
  unsigned u = __float_as_uint(f);
  u += 0x7FFF + ((u >> 16) & 1);
  return (unsigned short)(u >> 16);
}

// ---- Kernel 1: weight fp32 -> bf16 in MFMA A-fragment order (original k) ----
__global__ void pack_weight(const float* __restrict__ w,
                            unsigned short* __restrict__ wp) {
  const int t = blockIdx.x * 256 + threadIdx.x;   // 73728 threads
  const int lane = t & 63;
  const int ocf  = (t >> 6) & 15;
  const int kb   = t >> 10;
  const int oc   = ocf * 16 + (lane & 15);
  const int k0   = kb * 32 + (lane >> 4) * 8;
  const float* src = w + (size_t)oc * Ktot + k0;
  short8 pk;
  #pragma unroll
  for (int e = 0; e < 8; ++e) pk[e] = (short)f2bf(src[e]);
  *(short8*)(wp + (size_t)t * 8) = pk;
}

// ---- Kernel 2: fused sampling + MFMA, channel-split-K ----
__global__ __launch_bounds__(256, 6) void dcn_mfma(
    const float* __restrict__ x, const float* __restrict__ offset,
    const unsigned short* __restrict__ wp, float* __restrict__ out) {
  __shared__ unsigned short s_col[2][PT * KC];  // 2 x 4KB, XOR-swizzled [px][k]
  __shared__ float4 s_w[KK * PT];               // corner weights (pre-swapped)
  __shared__ int2   s_i[KK * PT];               // paired-corner row bases

  const int tid  = threadIdx.x;
  const int lane = tid & 63;
  const int wv   = tid >> 6;
  const int n    = blockIdx.y;
  const int p0   = blockIdx.x * PT;
  const int ch0  = blockIdx.z * CHPB;   // chunks [ch0, ch0+18) = channels z*128..

  // ---- Phase 0: bilinear coords; edge handling folded into weights ----
  for (int s = tid; s < KK * PT; s += 256) {
    const int k = s / PT, p = s % PT;
    const int pp = p0 + p;
    const int oy = pp / Ww, ox = pp % Ww;
    const int ky = k / 3, kx = k % 3;
    const float offy = offset[(size_t)(n * 18 + 2 * k    ) * HW + pp];
    const float offx = offset[(size_t)(n * 18 + 2 * k + 1) * HW + pp];
    const float py = offy + (float)(ky + oy - 1);
    const float px = offx + (float)(kx + ox - 1);
    const float fy0 = floorf(py), fx0 = floorf(px);
    const int iy0 = (int)fy0, ix0 = (int)fx0;
    const float wy1 = py - fy0, wx1 = px - fx0;
    const float wy0 = 1.f - wy1, wx0 = 1.f - wx1;
    const bool my0 = (iy0     >= 0) & (iy0     < Hh);
    const bool my1 = (iy0 + 1 >= 0) & (iy0 + 1 < Hh);
    const bool mx0 = (ix0     >= 0) & (ix0     < Ww);
    const bool mx1 = (ix0 + 1 >= 0) & (ix0 + 1 < Ww);
    const int cy0 = min(max(iy0,     0), Hh - 1);
    const int cy1 = min(max(iy0 + 1, 0), Hh - 1);
    const int bx  = min(max(ix0, 0), Ww - 2);   // dwordx2 base: [bx, bx+1]
    const bool sel = (ix0 == bx);
    const float wa = wx0 * wy0 * ((my0 && mx0) ? 1.f : 0.f);
    const float wb = wx1 * wy0 * ((my0 && mx1) ? 1.f : 0.f);
    const float wc = wx0 * wy1 * ((my1 && mx0) ? 1.f : 0.f);
    const float wd = wx1 * wy1 * ((my1 && mx1) ? 1.f : 0.f);
    float4 w4;  // pair-swap when x0 clamped off-base (masks make it exact)
    w4.x = sel ? wa : wb;  w4.y = sel ? wb : wa;
    w4.z = sel ? wc : wd;  w4.w = sel ? wd : wc;
    s_w[s] = w4;
    s_i[s] = make_int2(cy0 * Ww + bx, cy1 * Ww + bx);
  }

  floatx4 acc[4][2] = {};
  const int lm = lane & 15, lg = lane >> 4;
  const int spx  = tid & 31;        // sampling pixel
  const int skc0 = (tid >> 5) * 8;  // 8 consecutive k per thread
  __syncthreads();

  // ---- Prologue: sample chunk ch0 into buffer 0 ----
  {
    const int c0 = ch0 * KC;
    floatx2 ga[8], gb[8];
    #pragma unroll
    for (int i = 0; i < 8; ++i) {
      const int kg = c0 + skc0 + i;
      const int c = kg / 9, tap = kg - c * 9;
      const int2 o2 = s_i[tap * PT + spx];
      const float* xp = x + (size_t)(n * Cc + c) * HW;
      ga[i] = *(const floatx2*)(xp + o2.x);
      gb[i] = *(const floatx2*)(xp + o2.y);
    }
    short8 pk;
    #pragma unroll
    for (int i = 0; i < 8; ++i) {
      const int kg = c0 + skc0 + i;
      const int c = kg / 9, tap = kg - c * 9;
      const float4 w4 = s_w[tap * PT + spx];
      const float v = w4.x * ga[i].x + w4.y * ga[i].y
                    + w4.z * gb[i].x + w4.w * gb[i].y;
      pk[i] = (short)f2bf(v);
    }
    const int byte = spx * 128 + ((skc0 * 2) ^ ((spx & 7) << 4));
    *(short8*)((char*)s_col[0] + byte) = pk;
  }
  __syncthreads();

  // ---- Main pipeline over this block's 18 chunks ----
  for (int cl = 0; cl < CHPB; ++cl) {
    const int ch = ch0 + cl;
    const int cur = cl & 1;
    const bool more = (cl + 1 < CHPB);

    // 1) issue next chunk's gathers -> registers (hide under MFMA)
    floatx2 ga[8], gb[8];
    if (more) {
      const int c0n = (ch + 1) * KC;
      #pragma unroll
      for (int i = 0; i < 8; ++i) {
        const int kg = c0n + skc0 + i;
        const int c = kg / 9, tap = kg - c * 9;
        const int2 o2 = s_i[tap * PT + spx];
        const float* xp = x + (size_t)(n * Cc + c) * HW;
        ga[i] = *(const floatx2*)(xp + o2.x);
        gb[i] = *(const floatx2*)(xp + o2.y);
      }
    }

    // 2) MFMA on current buffer
    const int kb0 = ch * 2;
    #pragma unroll
    for (int ks = 0; ks < 2; ++ks) {
      short8 b[2];
      #pragma unroll
      for (int j = 0; j < 2; ++j) {
        const int px = j * 16 + lm;
        const int byte = px * 128 + (((ks * 64) + lg * 16) ^ ((px & 7) << 4));
        b[j] = *(const short8*)((const char*)s_col[cur] + byte);
      }
      const size_t abase = (size_t)(kb0 + ks) * 16 * 64 * 8;
      #pragma unroll
      for (int f = 0; f < 4; ++f) {
        const int ocf = wv * 4 + f;
        const short8 a = *(const short8*)(wp + abase + (size_t)(ocf * 64 + lane) * 8);
        acc[f][0] = __builtin_amdgcn_mfma_f32_16x16x32_bf16(a, b[0], acc[f][0], 0, 0, 0);
        acc[f][1] = __builtin_amdgcn_mfma_f32_16x16x32_bf16(a, b[1], acc[f][1], 0, 0, 0);
      }
    }

    // 3) bilinear + pack + single b128 write into the other buffer
    if (more) {
      const int c0n = (ch + 1) * KC;
      short8 pk;
      #pragma unroll
      for (int i = 0; i < 8; ++i) {
        const int kg = c0n + skc0 + i;
        const int c = kg / 9, tap = kg - c * 9;
        const float4 w4 = s_w[tap * PT + spx];
        const float v = w4.x * ga[i].x + w4.y * ga[i].y
                      + w4.z * gb[i].x + w4.w * gb[i].y;
        pk[i] = (short)f2bf(v);
      }
      const int byte = spx * 128 + ((skc0 * 2) ^ ((spx & 7) << 4));
      *(short8*)((char*)s_col[cur ^ 1] + byte) = pk;
    }
    __syncthreads();
  }

  // ---- Epilogue: atomicAdd partials (2 split-K contributions) ----
  #pragma unroll
  for (int f = 0; f < 4; ++f) {
    const int oc = wv * 64 + f * 16 + lg * 4;
    #pragma unroll
    for (int j = 0; j < 2; ++j) {
      const int px = p0 + j * 16 + lm;
      #pragma unroll
      for (int r = 0; r < 4; ++r) {
        atomicAdd(&out[(size_t)(n * OCc + oc + r) * HW + px], acc[f][j][r]);
      }
    }
  }
}

extern "C" void kernel_launch(void* const* d_in, const int* in_sizes, int n_in,
                              void* d_out, int out_size, void* d_ws, size_t ws_size,
                              hipStream_t stream) {
  const float* x      = (const float*)d_in[0];
  const float* offset = (const float*)d_in[1];
  const float* weight = (const float*)d_in[2];
  float* out = (float*)d_out;
  unsigned short* wp = (unsigned short*)d_ws;

  hipMemsetAsync(out, 0, (size_t)out_size * sizeof(float), stream);
  pack_weight<<<dim3(NKB * 16 * 64 / 256), dim3(256), 0, stream>>>(weight, wp);
  dcn_mfma<<<dim3(HW / PT, 4, 2), dim3(256), 0, stream>>>(x, offset, wp, out);
}